// Round 1
// baseline (1226.438 us; speedup 1.0000x reference)
//
#include <hip/hip_runtime.h>

// Problem constants (from reference)
#define PP   20000   // points
#define NN   16      // neighbors
#define DD   128     // model dim
#define HH   8       // heads
#define ANC  5       // equivariant channels
#define FF   512     // ffn hidden
#define PD   640     // D*AN per point
#define KVPAD 644    // padded LDS row stride (floats): 644%32=4 -> ~4-way max on dot reads, 16B aligned

// ---------------------------------------------------------------------------
// K1: q = Wq @ x, k = Wk @ x per point (v == q since reference uses to_q for v).
// 8 points per block, 320 threads. x is transposed into LDS as [a][e][pt]
// (pad 1032) so inner-loop x reads are float4x2 and weight reads are float4.
// ---------------------------------------------------------------------------
__global__ __launch_bounds__(320) void k_qkproj(
    const float* __restrict__ tgt, const float* __restrict__ Wq,
    const float* __restrict__ Wk, float* __restrict__ qo, float* __restrict__ ko)
{
  __shared__ float xs[5 * 1032];  // [a][e*8+pt], pad 1032 spreads banks by 8*(a+e)
  const int t = threadIdx.x;
  const int p0 = blockIdx.x * 8;
  const float* src = tgt + (size_t)p0 * PD;
#pragma unroll
  for (int i = 0; i < 16; ++i) {
    int lin = t + i * 320;          // 0..5119
    float v = src[lin];
    int pt = lin / PD;
    int rem = lin - pt * PD;
    int e = rem / 5;
    int a = rem - e * 5;
    xs[a * 1032 + e * 8 + pt] = v;
  }
  __syncthreads();
  const int a  = t % 5;
  const int d0 = t / 5;             // 0..63, also handles d0+64
  float q0[8] = {}, q1[8] = {}, k0[8] = {}, k1[8] = {};
  const float4* wq0 = reinterpret_cast<const float4*>(Wq + d0 * DD);
  const float4* wq1 = reinterpret_cast<const float4*>(Wq + (d0 + 64) * DD);
  const float4* wk0 = reinterpret_cast<const float4*>(Wk + d0 * DD);
  const float4* wk1 = reinterpret_cast<const float4*>(Wk + (d0 + 64) * DD);
  const float* xb = xs + a * 1032;
  for (int e4 = 0; e4 < 32; ++e4) {
    float4 A = wq0[e4], B = wq1[e4], C = wk0[e4], E = wk1[e4];
    float Aa[4] = {A.x, A.y, A.z, A.w};
    float Ba[4] = {B.x, B.y, B.z, B.w};
    float Ca[4] = {C.x, C.y, C.z, C.w};
    float Ea[4] = {E.x, E.y, E.z, E.w};
#pragma unroll
    for (int u = 0; u < 4; ++u) {
      const float4* xv = reinterpret_cast<const float4*>(xb + (e4 * 4 + u) * 8);
      float4 X0 = xv[0], X1 = xv[1];
      float Xa[8] = {X0.x, X0.y, X0.z, X0.w, X1.x, X1.y, X1.z, X1.w};
#pragma unroll
      for (int pt = 0; pt < 8; ++pt) {
        q0[pt] += Aa[u] * Xa[pt];
        q1[pt] += Ba[u] * Xa[pt];
        k0[pt] += Ca[u] * Xa[pt];
        k1[pt] += Ea[u] * Xa[pt];
      }
    }
  }
#pragma unroll
  for (int pt = 0; pt < 8; ++pt) {
    size_t base = (size_t)(p0 + pt) * PD;
    qo[base + d0 * 5 + a]        = q0[pt];
    qo[base + (d0 + 64) * 5 + a] = q1[pt];
    ko[base + d0 * 5 + a]        = k0[pt];
    ko[base + (d0 + 64) * 5 + a] = k1[pt];
  }
}

// ---------------------------------------------------------------------------
// K2: neighbor gather + attention. One point per block, 256 threads.
// dot[n,h] = sum_{d,a} q[p,h*16+d,a] * k[idx[n],h*16+d,a]
// att = softmax((dot+dist)/4) over n;  t2[e,a] = sum_n att[n,h(e)] * v[idx[n],e,a]
// v == q. Writes t2 (pre-Wo) in [p][e*5+a] layout into t2t (= d_out, reused).
// ---------------------------------------------------------------------------
__global__ __launch_bounds__(256) void k_attn(
    const float* __restrict__ q, const float* __restrict__ k,
    const int* __restrict__ idx, const float* __restrict__ dist,
    float* __restrict__ t2t)
{
  __shared__ float qs[PD];
  __shared__ float kv[NN * KVPAD];
  __shared__ float sc[128];
  __shared__ float att[128];
  __shared__ int sidx[NN];
  const int t = threadIdx.x;
  const int p = blockIdx.x;
  if (t < NN) sidx[t] = idx[p * NN + t];
  for (int i4 = t; i4 < 160; i4 += 256)
    *reinterpret_cast<float4*>(&qs[i4 * 4]) =
        *reinterpret_cast<const float4*>(&q[(size_t)p * PD + i4 * 4]);
  __syncthreads();
  // gather k rows of the 16 neighbors (float4, coalesced per row)
  for (int u = t; u < NN * 160; u += 256) {
    int n = u / 160, i4 = u - n * 160;
    *reinterpret_cast<float4*>(&kv[n * KVPAD + i4 * 4]) =
        *reinterpret_cast<const float4*>(&k[(size_t)sidx[n] * PD + i4 * 4]);
  }
  __syncthreads();
  if (t < 128) {
    int n = t & 15, h = t >> 4;
    const float* qh = qs + h * 80;            // (h*16+d)*5+a = h*80 + ...
    const float* kh = kv + n * KVPAD + h * 80;
    float acc = 0.f;
#pragma unroll
    for (int j = 0; j < 80; ++j) acc += qh[j] * kh[j];
    sc[h * 16 + n] = (acc + dist[(size_t)p * (NN * HH) + n * HH + h]) * 0.25f;
  }
  __syncthreads();
  // overwrite kv with gathered v (== q); softmax runs concurrently on sc
  for (int u = t; u < NN * 160; u += 256) {
    int n = u / 160, i4 = u - n * 160;
    *reinterpret_cast<float4*>(&kv[n * KVPAD + i4 * 4]) =
        *reinterpret_cast<const float4*>(&q[(size_t)sidx[n] * PD + i4 * 4]);
  }
  if (t < 8) {
    float m = -1e30f;
#pragma unroll
    for (int n = 0; n < 16; ++n) m = fmaxf(m, sc[t * 16 + n]);
    float s = 0.f;
    float ev[16];
#pragma unroll
    for (int n = 0; n < 16; ++n) { ev[n] = __expf(sc[t * 16 + n] - m); s += ev[n]; }
    float inv = 1.f / s;
#pragma unroll
    for (int n = 0; n < 16; ++n) att[t * 16 + n] = ev[n] * inv;
  }
  __syncthreads();
  for (int o = t; o < PD; o += 256) {
    int e = o / 5;
    int h = e >> 4;
    const float* at = att + h * 16;
    float acc = 0.f;
#pragma unroll
    for (int n = 0; n < 16; ++n) acc += at[n] * kv[n * KVPAD + o];
    t2t[(size_t)p * PD + o] = acc;
  }
}

// ---------------------------------------------------------------------------
// K3: fused Wo-projection + residual + LN1 + FFN(relu) + residual + LN2 +
// output transpose. 8 points (40 (p,a) rows) per block, 256 threads, 2500 blocks
// -> Wo/W1/W2 reused 40x per fetch (L2-resident).
// Thread t owns column d = t&127 for rows rh*20..rh*20+19 (rh = t>>7).
// Reads its own region of t2t (=d_out) first, writes same region last -> safe.
// ---------------------------------------------------------------------------
__global__ __launch_bounds__(256, 3) void k_ffn(
    const float* __restrict__ t2t, const float* __restrict__ tgt,
    const float* __restrict__ Wo, const float* __restrict__ W1,
    const float* __restrict__ b1, const float* __restrict__ W2,
    const float* __restrict__ b2, const float* __restrict__ g1,
    const float* __restrict__ be1, const float* __restrict__ g2,
    const float* __restrict__ be2, float* __restrict__ out)
{
  __shared__ float abuf[40 * 128];   // z / normalized y, row-major [row][d]
  __shared__ float hbuf[40 * 128];   // staging, hidden chunk, then v
  __shared__ float mrow[40], rrow[40];
  const int t = threadIdx.x;
  const int p0 = blockIdx.x * 8;
  const size_t gbase = (size_t)p0 * PD;
  // stage this block's t2 region (5120 floats, coalesced)
  for (int i = t; i < 5120; i += 256) hbuf[i] = t2t[gbase + i];
  __syncthreads();
  const int d  = t & 127;
  const int rh = t >> 7;   // 0/1
  int off[20];
#pragma unroll
  for (int j = 0; j < 20; ++j) {
    int rr = rh * 20 + j;
    int pp = rr / 5;
    off[j] = pp * PD + (rr - pp * 5);   // staged[pp*640 + e*5 + a]
  }
  // Wo: acc[j] = sum_e Wo[d,e] * t2[pp, e, a]   (LDS reads are wave-broadcast)
  float acc[20] = {};
  {
    const float4* wrow = reinterpret_cast<const float4*>(Wo + d * DD);
    for (int e4 = 0; e4 < 32; ++e4) {
      float4 W = wrow[e4];
      float Wa[4] = {W.x, W.y, W.z, W.w};
#pragma unroll
      for (int u = 0; u < 4; ++u) {
        int e = e4 * 4 + u;
#pragma unroll
        for (int j = 0; j < 20; ++j) acc[j] += Wa[u] * hbuf[off[j] + e * 5];
      }
    }
  }
  __syncthreads();
  // stage x (tgt) region, add residual, write z into abuf
  for (int i = t; i < 5120; i += 256) hbuf[i] = tgt[gbase + i];
  __syncthreads();
#pragma unroll
  for (int j = 0; j < 20; ++j)
    abuf[(rh * 20 + j) * 128 + d] = acc[j] + hbuf[off[j] + d * 5];
  __syncthreads();
  // LN1: 4 lanes per row, rotated element order to spread LDS banks
  if (t < 160) {
    int row = t >> 2, sub = t & 3;
    float s = 0.f, s2 = 0.f;
    const float* rp = abuf + row * 128;
#pragma unroll
    for (int i = 0; i < 32; ++i) {
      int el = (sub * 32 + i + row) & 127;
      float v = rp[el];
      s += v; s2 += v * v;
    }
    s  += __shfl_xor(s, 1);  s  += __shfl_xor(s, 2);
    s2 += __shfl_xor(s2, 1); s2 += __shfl_xor(s2, 2);
    if (sub == 0) {
      float m = s * 0.0078125f;
      float var = s2 * 0.0078125f - m * m;
      mrow[row] = m;
      rrow[row] = rsqrtf(var + 1e-5f);
    }
  }
  __syncthreads();
  for (int i = t; i < 5120; i += 256) {
    int row = i >> 7, dd = i & 127;
    abuf[i] = (abuf[i] - mrow[row]) * rrow[row] * g1[dd] + be1[dd];
  }
  __syncthreads();
  // FFN: hidden in 4 chunks of 128; out accumulates across chunks
  float oacc[20] = {};
  for (int c = 0; c < 4; ++c) {
    int f = c * 128 + d;
    float hacc[20] = {};
    const float4* w1row = reinterpret_cast<const float4*>(W1 + f * DD);
    for (int i4 = 0; i4 < 32; ++i4) {
      float4 W = w1row[i4];
#pragma unroll
      for (int j = 0; j < 20; ++j) {
        const float4 Y = *reinterpret_cast<const float4*>(
            &abuf[(rh * 20 + j) * 128 + i4 * 4]);
        hacc[j] += W.x * Y.x + W.y * Y.y + W.z * Y.z + W.w * Y.w;
      }
    }
    float bb = b1[f];
    __syncthreads();   // prior chunk's hbuf reads complete before overwrite
#pragma unroll
    for (int j = 0; j < 20; ++j)
      hbuf[(rh * 20 + j) * 128 + d] = fmaxf(hacc[j] + bb, 0.f);
    __syncthreads();
    const float4* w2row = reinterpret_cast<const float4*>(W2 + (size_t)d * FF + c * 128);
    for (int f4 = 0; f4 < 32; ++f4) {
      float4 W = w2row[f4];
#pragma unroll
      for (int j = 0; j < 20; ++j) {
        const float4 Hc = *reinterpret_cast<const float4*>(
            &hbuf[(rh * 20 + j) * 128 + f4 * 4]);
        oacc[j] += W.x * Hc.x + W.y * Hc.y + W.z * Hc.z + W.w * Hc.w;
      }
    }
  }
  __syncthreads();
  // residual (y + ff) into hbuf, then LN2 + transposed store
  float bo = b2[d];
#pragma unroll
  for (int j = 0; j < 20; ++j) {
    float v = oacc[j] + bo + abuf[(rh * 20 + j) * 128 + d];
    hbuf[(rh * 20 + j) * 128 + d] = v;
  }
  __syncthreads();
  if (t < 160) {
    int row = t >> 2, sub = t & 3;
    float s = 0.f, s2 = 0.f;
    const float* rp = hbuf + row * 128;
#pragma unroll
    for (int i = 0; i < 32; ++i) {
      int el = (sub * 32 + i + row) & 127;
      float v = rp[el];
      s += v; s2 += v * v;
    }
    s  += __shfl_xor(s, 1);  s  += __shfl_xor(s, 2);
    s2 += __shfl_xor(s2, 1); s2 += __shfl_xor(s2, 2);
    if (sub == 0) {
      float m = s * 0.0078125f;
      float var = s2 * 0.0078125f - m * m;
      mrow[row] = m;
      rrow[row] = rsqrtf(var + 1e-5f);
    }
  }
  __syncthreads();
  for (int i = t; i < 5120; i += 256) {
    int pp = i / PD;
    int rem = i - pp * PD;
    int dd = rem / 5;
    int a = rem - dd * 5;
    int row = pp * 5 + a;
    out[gbase + i] = (hbuf[row * 128 + dd] - mrow[row]) * rrow[row] * g2[dd] + be2[dd];
  }
}

// ---------------------------------------------------------------------------
extern "C" void kernel_launch(void* const* d_in, const int* in_sizes, int n_in,
                              void* d_out, int out_size, void* d_ws, size_t ws_size,
                              hipStream_t stream) {
  (void)in_sizes; (void)n_in; (void)out_size; (void)ws_size;
  const float* tgt  = (const float*)d_in[0];
  const int*   idx  = (const int*)d_in[1];     // jax default: int32
  // d_in[2] = cnt (unused by reference)
  const float* dist = (const float*)d_in[3];
  const float* Wq   = (const float*)d_in[4];
  const float* Wk   = (const float*)d_in[5];
  const float* Wo   = (const float*)d_in[6];
  const float* W1   = (const float*)d_in[7];
  const float* b1f  = (const float*)d_in[8];
  const float* W2   = (const float*)d_in[9];
  const float* b2f  = (const float*)d_in[10];
  const float* g1   = (const float*)d_in[11];
  const float* be1  = (const float*)d_in[12];
  const float* g2   = (const float*)d_in[13];
  const float* be2  = (const float*)d_in[14];
  float* out = (float*)d_out;

  float* q = (float*)d_ws;                 // [P][640]
  float* k = q + (size_t)PP * PD;          // [P][640]
  float* t2t = out;                        // t2 scratch aliases d_out (per-block
                                           // read-before-write in k_ffn is disjoint)

  k_qkproj<<<PP / 8, 320, 0, stream>>>(tgt, Wq, Wk, q, k);
  k_attn  <<<PP, 256, 0, stream>>>(q, k, idx, dist, t2t);
  k_ffn   <<<PP / 8, 256, 0, stream>>>(t2t, tgt, Wo, W1, b1f, W2, b2f,
                                       g1, be1, g2, be2, out);
}

// Round 2
// 532.269 us; speedup vs baseline: 2.3042x; 2.3042x over previous
//
#include <hip/hip_runtime.h>

#define PP   20000
#define NN   16
#define DD   128
#define HH   8
#define ANC  5
#define FF   512
#define PD   640
#define KVPAD 644
#define ROWS (PP * ANC)          // 100000 rows of [128]

typedef __attribute__((ext_vector_type(8))) short  bf8;     // 8 bf16 (4 VGPRs)
typedef __attribute__((ext_vector_type(8))) unsigned short ushort8;
typedef __attribute__((ext_vector_type(4))) float  f32x4;

__device__ inline float bf2f(unsigned short u) {
  union { unsigned int i; float f; } v; v.i = ((unsigned int)u) << 16; return v.f;
}
__device__ inline unsigned short f2bf(float f) {
  union { float f; unsigned int i; } v; v.f = f;
  unsigned int r = v.i + 0x7FFFu + ((v.i >> 16) & 1u);
  return (unsigned short)(r >> 16);
}

// ---------------------------------------------------------------------------
// K0: weight conversion fp32 -> bf16 (once per launch, ~5 us)
// ---------------------------------------------------------------------------
__global__ void k_wconv(const float* __restrict__ Wo, const float* __restrict__ W1,
                        const float* __restrict__ W2, unsigned short* __restrict__ Wob,
                        unsigned short* __restrict__ W1b, unsigned short* __restrict__ W2b)
{
  int i = blockIdx.x * 256 + threadIdx.x;
  if (i < 16384) Wob[i] = f2bf(Wo[i]);
  if (i < 65536) { W1b[i] = f2bf(W1[i]); W2b[i] = f2bf(W2[i]); }
}

// ---------------------------------------------------------------------------
// K1: q = Wq @ x, k = Wk @ x per point (v == q). Outputs bf16 in [p][e*5+a]
// layout; also writes xrow fp32 row-major [p*5+a][e] (aliases d_out).
// ---------------------------------------------------------------------------
__global__ __launch_bounds__(320) void k_qkproj(
    const float* __restrict__ tgt, const float* __restrict__ Wq,
    const float* __restrict__ Wk, unsigned short* __restrict__ qo,
    unsigned short* __restrict__ ko, float* __restrict__ xrow)
{
  __shared__ float xs[5 * 1032];
  const int t = threadIdx.x;
  const int p0 = blockIdx.x * 8;
  const float* src = tgt + (size_t)p0 * PD;
#pragma unroll
  for (int i = 0; i < 16; ++i) {
    int lin = t + i * 320;
    float v = src[lin];
    int pt = lin / PD;
    int rem = lin - pt * PD;
    int e = rem / 5;
    int a = rem - e * 5;
    xs[a * 1032 + e * 8 + pt] = v;
  }
  __syncthreads();
  // xrow: row-major transpose store (coalesced)
  {
    const int r0 = blockIdx.x * 40;
    for (int i = t; i < 5120; i += 320) {
      int row_l = i >> 7, col = i & 127;
      int pt = row_l / 5, a = row_l - pt * 5;
      xrow[(size_t)(r0 + row_l) * DD + col] = xs[a * 1032 + col * 8 + pt];
    }
  }
  const int a  = t % 5;
  const int d0 = t / 5;
  float q0[8] = {}, q1[8] = {}, k0[8] = {}, k1[8] = {};
  const float4* wq0 = reinterpret_cast<const float4*>(Wq + d0 * DD);
  const float4* wq1 = reinterpret_cast<const float4*>(Wq + (d0 + 64) * DD);
  const float4* wk0 = reinterpret_cast<const float4*>(Wk + d0 * DD);
  const float4* wk1 = reinterpret_cast<const float4*>(Wk + (d0 + 64) * DD);
  const float* xb = xs + a * 1032;
  for (int e4 = 0; e4 < 32; ++e4) {
    float4 A = wq0[e4], B = wq1[e4], C = wk0[e4], E = wk1[e4];
    float Aa[4] = {A.x, A.y, A.z, A.w};
    float Ba[4] = {B.x, B.y, B.z, B.w};
    float Ca[4] = {C.x, C.y, C.z, C.w};
    float Ea[4] = {E.x, E.y, E.z, E.w};
#pragma unroll
    for (int u = 0; u < 4; ++u) {
      const float4* xv = reinterpret_cast<const float4*>(xb + (e4 * 4 + u) * 8);
      float4 X0 = xv[0], X1 = xv[1];
      float Xa[8] = {X0.x, X0.y, X0.z, X0.w, X1.x, X1.y, X1.z, X1.w};
#pragma unroll
      for (int pt = 0; pt < 8; ++pt) {
        q0[pt] += Aa[u] * Xa[pt];
        q1[pt] += Ba[u] * Xa[pt];
        k0[pt] += Ca[u] * Xa[pt];
        k1[pt] += Ea[u] * Xa[pt];
      }
    }
  }
#pragma unroll
  for (int pt = 0; pt < 8; ++pt) {
    size_t base = (size_t)(p0 + pt) * PD;
    qo[base + d0 * 5 + a]        = f2bf(q0[pt]);
    qo[base + (d0 + 64) * 5 + a] = f2bf(q1[pt]);
    ko[base + d0 * 5 + a]        = f2bf(k0[pt]);
    ko[base + (d0 + 64) * 5 + a] = f2bf(k1[pt]);
  }
}

// ---------------------------------------------------------------------------
// K2: neighbor gather + attention (bf16 q/k in, bf16 row-major t2 out).
// ---------------------------------------------------------------------------
__global__ __launch_bounds__(256) void k_attn(
    const unsigned short* __restrict__ q, const unsigned short* __restrict__ k,
    const int* __restrict__ idx, const float* __restrict__ dist,
    unsigned short* __restrict__ t2r)
{
  __shared__ float qs[PD];
  __shared__ float kv[NN * KVPAD];
  __shared__ float sc[128];
  __shared__ float att[128];
  __shared__ float res[PD];
  __shared__ int sidx[NN];
  const int t = threadIdx.x;
  const int p = blockIdx.x;
  if (t < NN) sidx[t] = idx[p * NN + t];
  for (int c = t; c < 80; c += 256) {
    ushort8 v = *reinterpret_cast<const ushort8*>(&q[(size_t)p * PD + c * 8]);
#pragma unroll
    for (int j = 0; j < 8; ++j) qs[c * 8 + j] = bf2f(v[j]);
  }
  __syncthreads();
  for (int u = t; u < NN * 80; u += 256) {
    int n = u / 80, c = u - n * 80;
    ushort8 v = *reinterpret_cast<const ushort8*>(&k[(size_t)sidx[n] * PD + c * 8]);
#pragma unroll
    for (int j = 0; j < 8; ++j) kv[n * KVPAD + c * 8 + j] = bf2f(v[j]);
  }
  __syncthreads();
  if (t < 128) {
    int n = t & 15, h = t >> 4;
    const float* qh = qs + h * 80;
    const float* kh = kv + n * KVPAD + h * 80;
    float acc = 0.f;
#pragma unroll
    for (int j = 0; j < 80; ++j) acc += qh[j] * kh[j];
    sc[h * 16 + n] = (acc + dist[(size_t)p * (NN * HH) + n * HH + h]) * 0.25f;
  }
  __syncthreads();
  // overwrite kv with gathered v (== q)
  for (int u = t; u < NN * 80; u += 256) {
    int n = u / 80, c = u - n * 80;
    ushort8 v = *reinterpret_cast<const ushort8*>(&q[(size_t)sidx[n] * PD + c * 8]);
#pragma unroll
    for (int j = 0; j < 8; ++j) kv[n * KVPAD + c * 8 + j] = bf2f(v[j]);
  }
  if (t < 8) {
    float m = -1e30f;
#pragma unroll
    for (int n = 0; n < 16; ++n) m = fmaxf(m, sc[t * 16 + n]);
    float s = 0.f;
    float ev[16];
#pragma unroll
    for (int n = 0; n < 16; ++n) { ev[n] = __expf(sc[t * 16 + n] - m); s += ev[n]; }
    float inv = 1.f / s;
#pragma unroll
    for (int n = 0; n < 16; ++n) att[t * 16 + n] = ev[n] * inv;
  }
  __syncthreads();
  for (int o = t; o < PD; o += 256) {
    int e = o / 5;
    int h = e >> 4;
    const float* at = att + h * 16;
    float acc = 0.f;
#pragma unroll
    for (int n = 0; n < 16; ++n) acc += at[n] * kv[n * KVPAD + o];
    res[o] = acc;
  }
  __syncthreads();
  // t2 row-major bf16: t2r[(p*5+a)*128 + e]
  for (int i = t; i < PD; i += 256) {
    int arow = i >> 7, e = i & 127;
    t2r[((size_t)p * 5 + arow) * DD + e] = f2bf(res[e * 5 + arow]);
  }
}

// ---------------------------------------------------------------------------
// K3: MFMA-based Wo + residual + LN1 + FFN + residual + LN2 + transposed store.
// 80 rows (16 points) per block, 256 threads = 4 waves; waves split N into
// pairs of 16-wide n-tiles. z and y live in fp32 accumulator registers; LDS
// holds bf16 copies for MFMA A-operands (pad 136 -> 2-way conflicts only).
// xrow aliases d_out: block reads exactly the bytes it later overwrites.
// ---------------------------------------------------------------------------
__global__ __launch_bounds__(256, 2) void k_ffn_mfma(
    const unsigned short* __restrict__ t2r, const float* __restrict__ xrow,
    const unsigned short* __restrict__ Wob, const unsigned short* __restrict__ W1b,
    const float* __restrict__ b1, const unsigned short* __restrict__ W2b,
    const float* __restrict__ b2, const float* __restrict__ g1,
    const float* __restrict__ be1, const float* __restrict__ g2,
    const float* __restrict__ be2, float* __restrict__ out)
{
  __shared__ unsigned short SH[2 * 80 * 136];   // Yb | Hb ; reused as fp32 at end
  __shared__ float mrow[80], rrow[80];
  unsigned short* Yb = SH;
  unsigned short* Hb = SH + 80 * 136;
  const int t = threadIdx.x;
  const int w = t >> 6, l = t & 63;
  const int lc = l & 15;          // col within 16-tile / A-row selector
  const int kg = l >> 4;          // k-group (0..3)
  const int r0 = blockIdx.x * 80;
  const int c0 = (2 * w) * 16 + lc;   // wave's first output column
  const int c1 = c0 + 16;             // second

  f32x4 zac[5][2];
#pragma unroll
  for (int m = 0; m < 5; ++m)
#pragma unroll
    for (int n = 0; n < 2; ++n) zac[m][n] = (f32x4){0.f, 0.f, 0.f, 0.f};

  // ---- Wo GEMM: z = t2 @ Wo^T (A from global bf16 t2 rows, B from Wob) ----
  {
    bf8 wb[2][4];
#pragma unroll
    for (int nt = 0; nt < 2; ++nt)
#pragma unroll
      for (int kf = 0; kf < 4; ++kf)
        wb[nt][kf] = *reinterpret_cast<const bf8*>(
            &Wob[(size_t)((2 * w + nt) * 16 + lc) * DD + kf * 32 + kg * 8]);
#pragma unroll
    for (int mt = 0; mt < 5; ++mt) {
      const unsigned short* ap = t2r + (size_t)(r0 + mt * 16 + lc) * DD + kg * 8;
      bf8 a0 = *reinterpret_cast<const bf8*>(ap);
      bf8 a1 = *reinterpret_cast<const bf8*>(ap + 32);
      bf8 a2 = *reinterpret_cast<const bf8*>(ap + 64);
      bf8 a3 = *reinterpret_cast<const bf8*>(ap + 96);
#pragma unroll
      for (int nt = 0; nt < 2; ++nt) {
        zac[mt][nt] = __builtin_amdgcn_mfma_f32_16x16x32_bf16(a0, wb[nt][0], zac[mt][nt], 0, 0, 0);
        zac[mt][nt] = __builtin_amdgcn_mfma_f32_16x16x32_bf16(a1, wb[nt][1], zac[mt][nt], 0, 0, 0);
        zac[mt][nt] = __builtin_amdgcn_mfma_f32_16x16x32_bf16(a2, wb[nt][2], zac[mt][nt], 0, 0, 0);
        zac[mt][nt] = __builtin_amdgcn_mfma_f32_16x16x32_bf16(a3, wb[nt][3], zac[mt][nt], 0, 0, 0);
      }
    }
  }
  // ---- residual x; write z (bf16) for stats ----
#pragma unroll
  for (int mt = 0; mt < 5; ++mt) {
    int rb = mt * 16 + kg * 4;
#pragma unroll
    for (int j = 0; j < 4; ++j) {
      int row = rb + j;
      const float* xp = xrow + (size_t)(r0 + row) * DD;
      zac[mt][0][j] += xp[c0];
      zac[mt][1][j] += xp[c1];
      Yb[row * 136 + c0] = f2bf(zac[mt][0][j]);
      Yb[row * 136 + c1] = f2bf(zac[mt][1][j]);
    }
  }
  __syncthreads();
  // ---- LN1 stats (from bf16 copy; ~2e-4 impact) ----
  if (t < 160) {
    int row = t >> 1, hf = t & 1;
    const unsigned short* rp = Yb + row * 136 + hf * 64;
    float s = 0.f, s2 = 0.f;
#pragma unroll
    for (int c8 = 0; c8 < 8; ++c8) {
      bf8 v8 = *reinterpret_cast<const bf8*>(rp + c8 * 8);
#pragma unroll
      for (int j = 0; j < 8; ++j) {
        float f = bf2f((unsigned short)v8[j]);
        s += f; s2 += f * f;
      }
    }
    s += __shfl_xor(s, 1); s2 += __shfl_xor(s2, 1);
    if (!hf) {
      float mm = s * (1.f / 128.f);
      float vv = s2 * (1.f / 128.f) - mm * mm;
      mrow[row] = mm;
      rrow[row] = rsqrtf(vv + 1e-5f);
    }
  }
  __syncthreads();
  // ---- normalize in regs (y kept fp32), write y bf16 to Yb ----
  {
    float g1a = g1[c0], g1b = g1[c1], e1a = be1[c0], e1b = be1[c1];
#pragma unroll
    for (int mt = 0; mt < 5; ++mt) {
      int rb = mt * 16 + kg * 4;
#pragma unroll
      for (int j = 0; j < 4; ++j) {
        int row = rb + j;
        float mm = mrow[row], rr = rrow[row];
        float y0 = (zac[mt][0][j] - mm) * rr * g1a + e1a;
        float y1 = (zac[mt][1][j] - mm) * rr * g1b + e1b;
        zac[mt][0][j] = y0; zac[mt][1][j] = y1;
        Yb[row * 136 + c0] = f2bf(y0);
        Yb[row * 136 + c1] = f2bf(y1);
      }
    }
  }
  __syncthreads();
  // ---- FFN: 4 chunks of 128 hidden; H staged bf16 in Hb ----
  f32x4 oac[5][2];
#pragma unroll
  for (int m = 0; m < 5; ++m)
#pragma unroll
    for (int n = 0; n < 2; ++n) oac[m][n] = (f32x4){0.f, 0.f, 0.f, 0.f};

  for (int c = 0; c < 4; ++c) {
    bf8 w1f[2][4];
#pragma unroll
    for (int nt = 0; nt < 2; ++nt)
#pragma unroll
      for (int kf = 0; kf < 4; ++kf)
        w1f[nt][kf] = *reinterpret_cast<const bf8*>(
            &W1b[(size_t)(c * 128 + (2 * w + nt) * 16 + lc) * DD + kf * 32 + kg * 8]);
    f32x4 hac[5][2];
#pragma unroll
    for (int m = 0; m < 5; ++m)
#pragma unroll
      for (int n = 0; n < 2; ++n) hac[m][n] = (f32x4){0.f, 0.f, 0.f, 0.f};
#pragma unroll
    for (int mt = 0; mt < 5; ++mt) {
      const unsigned short* yp = Yb + (mt * 16 + lc) * 136 + kg * 8;
      bf8 a0 = *reinterpret_cast<const bf8*>(yp);
      bf8 a1 = *reinterpret_cast<const bf8*>(yp + 32);
      bf8 a2 = *reinterpret_cast<const bf8*>(yp + 64);
      bf8 a3 = *reinterpret_cast<const bf8*>(yp + 96);
#pragma unroll
      for (int nt = 0; nt < 2; ++nt) {
        hac[mt][nt] = __builtin_amdgcn_mfma_f32_16x16x32_bf16(a0, w1f[nt][0], hac[mt][nt], 0, 0, 0);
        hac[mt][nt] = __builtin_amdgcn_mfma_f32_16x16x32_bf16(a1, w1f[nt][1], hac[mt][nt], 0, 0, 0);
        hac[mt][nt] = __builtin_amdgcn_mfma_f32_16x16x32_bf16(a2, w1f[nt][2], hac[mt][nt], 0, 0, 0);
        hac[mt][nt] = __builtin_amdgcn_mfma_f32_16x16x32_bf16(a3, w1f[nt][3], hac[mt][nt], 0, 0, 0);
      }
    }
    float b1a = b1[c * 128 + c0], b1b = b1[c * 128 + c1];
    __syncthreads();   // prior chunk's Hb reads done
#pragma unroll
    for (int mt = 0; mt < 5; ++mt) {
      int rb = mt * 16 + kg * 4;
#pragma unroll
      for (int j = 0; j < 4; ++j) {
        int row = rb + j;
        Hb[row * 136 + c0] = f2bf(fmaxf(hac[mt][0][j] + b1a, 0.f));
        Hb[row * 136 + c1] = f2bf(fmaxf(hac[mt][1][j] + b1b, 0.f));
      }
    }
    __syncthreads();
    bf8 w2f[2][4];
#pragma unroll
    for (int nt = 0; nt < 2; ++nt)
#pragma unroll
      for (int kf = 0; kf < 4; ++kf)
        w2f[nt][kf] = *reinterpret_cast<const bf8*>(
            &W2b[(size_t)((2 * w + nt) * 16 + lc) * FF + c * 128 + kf * 32 + kg * 8]);
#pragma unroll
    for (int mt = 0; mt < 5; ++mt) {
      const unsigned short* hp = Hb + (mt * 16 + lc) * 136 + kg * 8;
      bf8 a0 = *reinterpret_cast<const bf8*>(hp);
      bf8 a1 = *reinterpret_cast<const bf8*>(hp + 32);
      bf8 a2 = *reinterpret_cast<const bf8*>(hp + 64);
      bf8 a3 = *reinterpret_cast<const bf8*>(hp + 96);
#pragma unroll
      for (int nt = 0; nt < 2; ++nt) {
        oac[mt][nt] = __builtin_amdgcn_mfma_f32_16x16x32_bf16(a0, w2f[nt][0], oac[mt][nt], 0, 0, 0);
        oac[mt][nt] = __builtin_amdgcn_mfma_f32_16x16x32_bf16(a1, w2f[nt][1], oac[mt][nt], 0, 0, 0);
        oac[mt][nt] = __builtin_amdgcn_mfma_f32_16x16x32_bf16(a2, w2f[nt][2], oac[mt][nt], 0, 0, 0);
        oac[mt][nt] = __builtin_amdgcn_mfma_f32_16x16x32_bf16(a3, w2f[nt][3], oac[mt][nt], 0, 0, 0);
      }
    }
  }
  // ---- v = y + ff + b2 ; LN2 ; transposed store ----
  {
    float b2a = b2[c0], b2b = b2[c1];
#pragma unroll
    for (int mt = 0; mt < 5; ++mt) {
      int rb = mt * 16 + kg * 4;
#pragma unroll
      for (int j = 0; j < 4; ++j) {
        int row = rb + j;
        float v0 = zac[mt][0][j] + oac[mt][0][j] + b2a;
        float v1 = zac[mt][1][j] + oac[mt][1][j] + b2b;
        oac[mt][0][j] = v0; oac[mt][1][j] = v1;
        Yb[row * 136 + c0] = f2bf(v0);
        Yb[row * 136 + c1] = f2bf(v1);
      }
    }
  }
  __syncthreads();
  if (t < 160) {
    int row = t >> 1, hf = t & 1;
    const unsigned short* rp = Yb + row * 136 + hf * 64;
    float s = 0.f, s2 = 0.f;
#pragma unroll
    for (int c8 = 0; c8 < 8; ++c8) {
      bf8 v8 = *reinterpret_cast<const bf8*>(rp + c8 * 8);
#pragma unroll
      for (int j = 0; j < 8; ++j) {
        float f = bf2f((unsigned short)v8[j]);
        s += f; s2 += f * f;
      }
    }
    s += __shfl_xor(s, 1); s2 += __shfl_xor(s2, 1);
    if (!hf) {
      float mm = s * (1.f / 128.f);
      float vv = s2 * (1.f / 128.f) - mm * mm;
      mrow[row] = mm;
      rrow[row] = rsqrtf(vv + 1e-5f);
    }
  }
  __syncthreads();
  {
    float* fb = (float*)SH;     // 80 x 132 fp32 staging (fits in Yb|Hb)
    float g2a = g2[c0], g2b = g2[c1], e2a = be2[c0], e2b = be2[c1];
#pragma unroll
    for (int mt = 0; mt < 5; ++mt) {
      int rb = mt * 16 + kg * 4;
#pragma unroll
      for (int j = 0; j < 4; ++j) {
        int row = rb + j;
        float mm = mrow[row], rr = rrow[row];
        fb[row * 132 + c0] = (oac[mt][0][j] - mm) * rr * g2a + e2a;
        fb[row * 132 + c1] = (oac[mt][1][j] - mm) * rr * g2b + e2b;
      }
    }
    __syncthreads();
    const size_t ob = (size_t)blockIdx.x * 16 * PD;
    for (int i = t; i < 10240; i += 256) {
      int pl = i / PD, rem = i - pl * PD;
      int d = rem / 5, a = rem - d * 5;
      out[ob + i] = fb[(pl * 5 + a) * 132 + d];
    }
  }
}

// ---------------------------------------------------------------------------
extern "C" void kernel_launch(void* const* d_in, const int* in_sizes, int n_in,
                              void* d_out, int out_size, void* d_ws, size_t ws_size,
                              hipStream_t stream) {
  (void)in_sizes; (void)n_in; (void)out_size; (void)ws_size;
  const float* tgt  = (const float*)d_in[0];
  const int*   idx  = (const int*)d_in[1];
  const float* dist = (const float*)d_in[3];
  const float* Wq   = (const float*)d_in[4];
  const float* Wk   = (const float*)d_in[5];
  const float* Wo   = (const float*)d_in[6];
  const float* W1   = (const float*)d_in[7];
  const float* b1f  = (const float*)d_in[8];
  const float* W2   = (const float*)d_in[9];
  const float* b2f  = (const float*)d_in[10];
  const float* g1   = (const float*)d_in[11];
  const float* be1  = (const float*)d_in[12];
  const float* g2   = (const float*)d_in[13];
  const float* be2  = (const float*)d_in[14];
  float* out = (float*)d_out;

  // ws: q(bf16) | k(bf16) | t2row(bf16) | Wob | W1b | W2b  = ~77.1 MB
  unsigned short* qb  = (unsigned short*)d_ws;
  unsigned short* kb  = qb + (size_t)PP * PD;
  unsigned short* t2r = kb + (size_t)PP * PD;
  unsigned short* Wob = t2r + (size_t)ROWS * DD;
  unsigned short* W1b = Wob + 16384;
  unsigned short* W2b = W1b + 65536;
  float* xrow = out;   // aliases d_out: k_ffn block reads its own region before writing it

  k_wconv  <<<256, 256, 0, stream>>>(Wo, W1, W2, Wob, W1b, W2b);
  k_qkproj <<<PP / 8, 320, 0, stream>>>(tgt, Wq, Wk, qb, kb, xrow);
  k_attn   <<<PP, 256, 0, stream>>>(qb, kb, idx, dist, t2r);
  k_ffn_mfma<<<ROWS / 80, 256, 0, stream>>>(t2r, xrow, Wob, W1b, b1f, W2b, b2f,
                                            g1, be1, g2, be2, out);
}

// Round 5
// 356.908 us; speedup vs baseline: 3.4363x; 1.4913x over previous
//
#include <hip/hip_runtime.h>

#define PP   20000
#define NN   16
#define DD   128
#define HH   8
#define ANC  5
#define FF   512
#define PD   640
#define ROWS (PP * ANC)          // 100000 rows of [128]
#define KSTRIDE 648              // shorts; LDS K rows: 16B-aligned, banks spread
#define SEG  20480               // shorts per d_out segment (80 rows x 128 x 2 halves)

// d_out overlay (per 80-row segment s, byte base s*40960):
//   [0,20480)B  : bf16 x rows   (row r -> s=r/80, local=r%80, +local*256B)
//   [20480,40960)B : bf16 t2 rows (same row mapping)
// k_ffn block s reads exactly segment s and finally overwrites it with fp32 out.

typedef __attribute__((ext_vector_type(8))) short  bf8;     // 8 bf16 (4 VGPRs)
typedef __attribute__((ext_vector_type(8))) unsigned short ushort8;
typedef __attribute__((ext_vector_type(4))) unsigned short us4;
typedef __attribute__((ext_vector_type(4))) float  f32x4;

__device__ inline float bf2f(unsigned short u) {
  union { unsigned int i; float f; } v; v.i = ((unsigned int)u) << 16; return v.f;
}
__device__ inline unsigned short f2bf(float f) {
  union { float f; unsigned int i; } v; v.f = f;
  unsigned int r = v.i + 0x7FFFu + ((v.i >> 16) & 1u);
  return (unsigned short)(r >> 16);
}

// ---------------------------------------------------------------------------
// K0: weight conversion fp32 -> bf16 (once per launch)
// ---------------------------------------------------------------------------
__global__ void k_wconv(const float* __restrict__ Wo, const float* __restrict__ W1,
                        const float* __restrict__ W2, const float* __restrict__ Wq,
                        const float* __restrict__ Wk,
                        unsigned short* __restrict__ Wob, unsigned short* __restrict__ W1b,
                        unsigned short* __restrict__ W2b, unsigned short* __restrict__ Wqb,
                        unsigned short* __restrict__ Wkb)
{
  int i = blockIdx.x * 256 + threadIdx.x;
  if (i < 16384) { Wob[i] = f2bf(Wo[i]); Wqb[i] = f2bf(Wq[i]); Wkb[i] = f2bf(Wk[i]); }
  if (i < 65536) { W1b[i] = f2bf(W1[i]); W2b[i] = f2bf(W2[i]); }
}

// ---------------------------------------------------------------------------
// K1a: transpose tgt [p][e*5+a] -> bf16 x rows [p*5+a][e] into d_out overlay.
// ---------------------------------------------------------------------------
__global__ __launch_bounds__(320) void k_xpose(
    const float* __restrict__ tgt, unsigned short* __restrict__ xb)
{
  __shared__ float xs[5 * 1032];
  const int t = threadIdx.x;
  const int p0 = blockIdx.x * 8;
  const float* src = tgt + (size_t)p0 * PD;
#pragma unroll
  for (int i = 0; i < 16; ++i) {
    int lin = t + i * 320;
    float v = src[lin];
    int pt = lin / PD;
    int rem = lin - pt * PD;
    int e = rem / 5;
    int a = rem - e * 5;
    xs[a * 1032 + e * 8 + pt] = v;
  }
  __syncthreads();
  // 40 rows per block; rows r0..r0+39 live in segment r0/80, half (blockIdx&1)
  const size_t base = (size_t)(blockIdx.x >> 1) * SEG + (size_t)(blockIdx.x & 1) * 5120;
  for (int i = t; i < 5120; i += 320) {
    int row_l = i >> 7, col = i & 127;
    int pt = row_l / 5, a = row_l - pt * 5;
    xb[base + i] = f2bf(xs[a * 1032 + col * 8 + pt]);
  }
}

// ---------------------------------------------------------------------------
// K1b: MFMA GEMM q = x@Wq^T, k = x@Wk^T; writes combined kq rows:
// kqb[p][0..640) = k (layout e*5+a), kqb[p][640..1280) = q.
// ---------------------------------------------------------------------------
__global__ __launch_bounds__(256) void k_qk_gemm(
    const unsigned short* __restrict__ xb, const unsigned short* __restrict__ Wqb,
    const unsigned short* __restrict__ Wkb, unsigned short* __restrict__ kqb)
{
  __shared__ unsigned short Sb[80 * 136];
  const int t = threadIdx.x;
  const int w = t >> 6, l = t & 63;
  const int lc = l & 15, kg = l >> 4;
  const int p0 = blockIdx.x * 16;
  const unsigned short* xseg = xb + (size_t)blockIdx.x * SEG;  // 80 rows x 128

  f32x4 zq[5][2], zk[5][2];
#pragma unroll
  for (int m = 0; m < 5; ++m)
#pragma unroll
    for (int n = 0; n < 2; ++n) {
      zq[m][n] = (f32x4){0.f, 0.f, 0.f, 0.f};
      zk[m][n] = (f32x4){0.f, 0.f, 0.f, 0.f};
    }
  bf8 wq[2][4], wk[2][4];
#pragma unroll
  for (int nt = 0; nt < 2; ++nt)
#pragma unroll
    for (int kf = 0; kf < 4; ++kf) {
      size_t wo = (size_t)((2 * w + nt) * 16 + lc) * DD + kf * 32 + kg * 8;
      wq[nt][kf] = *reinterpret_cast<const bf8*>(&Wqb[wo]);
      wk[nt][kf] = *reinterpret_cast<const bf8*>(&Wkb[wo]);
    }
#pragma unroll
  for (int mt = 0; mt < 5; ++mt) {
    const unsigned short* ap = xseg + (mt * 16 + lc) * DD + kg * 8;
    bf8 a0 = *reinterpret_cast<const bf8*>(ap);
    bf8 a1 = *reinterpret_cast<const bf8*>(ap + 32);
    bf8 a2 = *reinterpret_cast<const bf8*>(ap + 64);
    bf8 a3 = *reinterpret_cast<const bf8*>(ap + 96);
#pragma unroll
    for (int nt = 0; nt < 2; ++nt) {
      zq[mt][nt] = __builtin_amdgcn_mfma_f32_16x16x32_bf16(a0, wq[nt][0], zq[mt][nt], 0, 0, 0);
      zq[mt][nt] = __builtin_amdgcn_mfma_f32_16x16x32_bf16(a1, wq[nt][1], zq[mt][nt], 0, 0, 0);
      zq[mt][nt] = __builtin_amdgcn_mfma_f32_16x16x32_bf16(a2, wq[nt][2], zq[mt][nt], 0, 0, 0);
      zq[mt][nt] = __builtin_amdgcn_mfma_f32_16x16x32_bf16(a3, wq[nt][3], zq[mt][nt], 0, 0, 0);
      zk[mt][nt] = __builtin_amdgcn_mfma_f32_16x16x32_bf16(a0, wk[nt][0], zk[mt][nt], 0, 0, 0);
      zk[mt][nt] = __builtin_amdgcn_mfma_f32_16x16x32_bf16(a1, wk[nt][1], zk[mt][nt], 0, 0, 0);
      zk[mt][nt] = __builtin_amdgcn_mfma_f32_16x16x32_bf16(a2, wk[nt][2], zk[mt][nt], 0, 0, 0);
      zk[mt][nt] = __builtin_amdgcn_mfma_f32_16x16x32_bf16(a3, wk[nt][3], zk[mt][nt], 0, 0, 0);
    }
  }
  // ---- epilogue: Q half (offset 640), then K half (offset 0) via LDS ----
#pragma unroll
  for (int mt = 0; mt < 5; ++mt)
#pragma unroll
    for (int j = 0; j < 4; ++j)
#pragma unroll
      for (int nt = 0; nt < 2; ++nt)
        Sb[(mt * 16 + kg * 4 + j) * 136 + (2 * w + nt) * 16 + lc] = f2bf(zq[mt][nt][j]);
  __syncthreads();
  for (int i = t; i < 10240; i += 256) {
    int pl = i / 640, rem = i - pl * 640;
    int d = rem / 5, a = rem - d * 5;
    kqb[(size_t)(p0 + pl) * 1280 + 640 + rem] = Sb[(pl * 5 + a) * 136 + d];
  }
  __syncthreads();
#pragma unroll
  for (int mt = 0; mt < 5; ++mt)
#pragma unroll
    for (int j = 0; j < 4; ++j)
#pragma unroll
      for (int nt = 0; nt < 2; ++nt)
        Sb[(mt * 16 + kg * 4 + j) * 136 + (2 * w + nt) * 16 + lc] = f2bf(zk[mt][nt][j]);
  __syncthreads();
  for (int i = t; i < 10240; i += 256) {
    int pl = i / 640, rem = i - pl * 640;
    int d = rem / 5, a = rem - d * 5;
    kqb[(size_t)(p0 + pl) * 1280 + rem] = Sb[(pl * 5 + a) * 136 + d];
  }
}

// ---------------------------------------------------------------------------
// K2: attention. One point per block. K gathered to bf16 LDS; V preloaded to
// registers before the dot phase. Writes t2 rows into d_out overlay half 2.
// ---------------------------------------------------------------------------
__global__ __launch_bounds__(256, 4) void k_attn(
    const unsigned short* __restrict__ kqb, const int* __restrict__ idx,
    const float* __restrict__ dist, unsigned short* __restrict__ t2b)
{
  __shared__ unsigned short ksh[NN * KSTRIDE];
  __shared__ unsigned short qsh[648];
  __shared__ float sc[128];
  __shared__ float att[128];
  __shared__ int sidx[NN];
  const int t = threadIdx.x;
  const int p = blockIdx.x;
  if (t < NN) sidx[t] = idx[p * NN + t];
  if (t < 80)
    *reinterpret_cast<ushort8*>(&qsh[t * 8]) =
        *reinterpret_cast<const ushort8*>(&kqb[(size_t)p * 1280 + 640 + t * 8]);
  float dv = 0.f;
  if (t < 128) dv = dist[(size_t)p * 128 + (t & 15) * 8 + (t >> 4)];
  __syncthreads();
  // V preload into registers (hides under gather + dot)
  us4 vreg[16];
  const int o0 = (t < 160) ? t * 4 : 0;
  if (t < 160) {
#pragma unroll
    for (int n = 0; n < 16; ++n)
      vreg[n] = *reinterpret_cast<const us4*>(&kqb[(size_t)sidx[n] * 1280 + 640 + o0]);
  }
  // gather K halves -> LDS (raw bf16, b128 writes)
#pragma unroll
  for (int it = 0; it < 5; ++it) {
    int u = t + it * 256;
    int n = u / 80, c = u - n * 80;
    *reinterpret_cast<ushort8*>(&ksh[n * KSTRIDE + c * 8]) =
        *reinterpret_cast<const ushort8*>(&kqb[(size_t)sidx[n] * 1280 + c * 8]);
  }
  __syncthreads();
  if (t < 128) {
    int n = t & 15, h = t >> 4;
    const unsigned short* kp = &ksh[n * KSTRIDE + h * 80];
    const unsigned short* qp = &qsh[h * 80];
    float acc = 0.f;
#pragma unroll
    for (int j = 0; j < 10; ++j) {
      ushort8 kv8 = *reinterpret_cast<const ushort8*>(&kp[j * 8]);
      ushort8 qv8 = *reinterpret_cast<const ushort8*>(&qp[j * 8]);
#pragma unroll
      for (int jj = 0; jj < 8; ++jj) acc += bf2f(kv8[jj]) * bf2f(qv8[jj]);
    }
    sc[h * 16 + n] = (acc + dv) * 0.25f;
  }
  __syncthreads();
  if (t < 8) {
    float m = -1e30f;
#pragma unroll
    for (int n = 0; n < 16; ++n) m = fmaxf(m, sc[t * 16 + n]);
    float s = 0.f;
    float ev[16];
#pragma unroll
    for (int n = 0; n < 16; ++n) { ev[n] = __expf(sc[t * 16 + n] - m); s += ev[n]; }
    float inv = 1.f / s;
#pragma unroll
    for (int n = 0; n < 16; ++n) att[t * 16 + n] = ev[n] * inv;
  }
  __syncthreads();
  if (t < 160) {
    const int h = o0 / 80;     // 4-elem chunk never straddles a head (4 | 80)
    float facc[4] = {0.f, 0.f, 0.f, 0.f};
#pragma unroll
    for (int n = 0; n < 16; ++n) {
      float aw = att[h * 16 + n];
#pragma unroll
      for (int j = 0; j < 4; ++j) facc[j] += aw * bf2f(vreg[n][j]);
    }
    // t2 row (p*5+a): segment p>>4, local (p&15)*5+a, second overlay half
    unsigned short* t2p = t2b + (size_t)(p >> 4) * SEG + 10240 + ((p & 15) * 5) * 128;
#pragma unroll
    for (int j = 0; j < 4; ++j) {
      int o = o0 + j;
      int e = o / 5, a = o - e * 5;
      t2p[a * 128 + e] = f2bf(facc[j]);
    }
  }
}

// ---------------------------------------------------------------------------
// K3: MFMA Wo + residual + LN1 + FFN + residual + LN2 + transposed store.
// Block bid reads bf16 x/t2 from d_out segment bid, writes fp32 out over the
// same segment at the end (all reads barrier-separated from the store).
// ---------------------------------------------------------------------------
__global__ __launch_bounds__(256, 2) void k_ffn_mfma(
    float* out, const unsigned short* __restrict__ Wob,
    const unsigned short* __restrict__ W1b, const float* __restrict__ b1,
    const unsigned short* __restrict__ W2b, const float* __restrict__ b2,
    const float* __restrict__ g1, const float* __restrict__ be1,
    const float* __restrict__ g2, const float* __restrict__ be2)
{
  __shared__ unsigned short SH[2 * 80 * 136];
  __shared__ float mrow[80], rrow[80];
  unsigned short* Yb = SH;
  unsigned short* Hb = SH + 80 * 136;
  const int t = threadIdx.x;
  const int w = t >> 6, l = t & 63;
  const int lc = l & 15;
  const int kg = l >> 4;
  const int c0 = (2 * w) * 16 + lc;
  const int c1 = c0 + 16;
  const unsigned short* xseg = (const unsigned short*)out + (size_t)blockIdx.x * SEG;
  const unsigned short* t2seg = xseg + 10240;

  f32x4 zac[5][2];
#pragma unroll
  for (int m = 0; m < 5; ++m)
#pragma unroll
    for (int n = 0; n < 2; ++n) zac[m][n] = (f32x4){0.f, 0.f, 0.f, 0.f};

  {
    bf8 wb[2][4];
#pragma unroll
    for (int nt = 0; nt < 2; ++nt)
#pragma unroll
      for (int kf = 0; kf < 4; ++kf)
        wb[nt][kf] = *reinterpret_cast<const bf8*>(
            &Wob[(size_t)((2 * w + nt) * 16 + lc) * DD + kf * 32 + kg * 8]);
#pragma unroll
    for (int mt = 0; mt < 5; ++mt) {
      const unsigned short* ap = t2seg + (mt * 16 + lc) * DD + kg * 8;
      bf8 a0 = *reinterpret_cast<const bf8*>(ap);
      bf8 a1 = *reinterpret_cast<const bf8*>(ap + 32);
      bf8 a2 = *reinterpret_cast<const bf8*>(ap + 64);
      bf8 a3 = *reinterpret_cast<const bf8*>(ap + 96);
#pragma unroll
      for (int nt = 0; nt < 2; ++nt) {
        zac[mt][nt] = __builtin_amdgcn_mfma_f32_16x16x32_bf16(a0, wb[nt][0], zac[mt][nt], 0, 0, 0);
        zac[mt][nt] = __builtin_amdgcn_mfma_f32_16x16x32_bf16(a1, wb[nt][1], zac[mt][nt], 0, 0, 0);
        zac[mt][nt] = __builtin_amdgcn_mfma_f32_16x16x32_bf16(a2, wb[nt][2], zac[mt][nt], 0, 0, 0);
        zac[mt][nt] = __builtin_amdgcn_mfma_f32_16x16x32_bf16(a3, wb[nt][3], zac[mt][nt], 0, 0, 0);
      }
    }
  }
#pragma unroll
  for (int mt = 0; mt < 5; ++mt) {
    int rb = mt * 16 + kg * 4;
#pragma unroll
    for (int j = 0; j < 4; ++j) {
      int row = rb + j;
      zac[mt][0][j] += bf2f(xseg[row * DD + c0]);
      zac[mt][1][j] += bf2f(xseg[row * DD + c1]);
      Yb[row * 136 + c0] = f2bf(zac[mt][0][j]);
      Yb[row * 136 + c1] = f2bf(zac[mt][1][j]);
    }
  }
  __syncthreads();
  if (t < 160) {
    int row = t >> 1, hf = t & 1;
    const unsigned short* rp = Yb + row * 136 + hf * 64;
    float s = 0.f, s2 = 0.f;
#pragma unroll
    for (int c8 = 0; c8 < 8; ++c8) {
      bf8 v8 = *reinterpret_cast<const bf8*>(rp + c8 * 8);
#pragma unroll
      for (int j = 0; j < 8; ++j) {
        float f = bf2f((unsigned short)v8[j]);
        s += f; s2 += f * f;
      }
    }
    s += __shfl_xor(s, 1); s2 += __shfl_xor(s2, 1);
    if (!hf) {
      float mm = s * (1.f / 128.f);
      float vv = s2 * (1.f / 128.f) - mm * mm;
      mrow[row] = mm;
      rrow[row] = rsqrtf(vv + 1e-5f);
    }
  }
  __syncthreads();
  {
    float g1a = g1[c0], g1b = g1[c1], e1a = be1[c0], e1b = be1[c1];
#pragma unroll
    for (int mt = 0; mt < 5; ++mt) {
      int rb = mt * 16 + kg * 4;
#pragma unroll
      for (int j = 0; j < 4; ++j) {
        int row = rb + j;
        float mm = mrow[row], rr = rrow[row];
        float y0 = (zac[mt][0][j] - mm) * rr * g1a + e1a;
        float y1 = (zac[mt][1][j] - mm) * rr * g1b + e1b;
        zac[mt][0][j] = y0; zac[mt][1][j] = y1;
        Yb[row * 136 + c0] = f2bf(y0);
        Yb[row * 136 + c1] = f2bf(y1);
      }
    }
  }
  __syncthreads();
  f32x4 oac[5][2];
#pragma unroll
  for (int m = 0; m < 5; ++m)
#pragma unroll
    for (int n = 0; n < 2; ++n) oac[m][n] = (f32x4){0.f, 0.f, 0.f, 0.f};

  for (int c = 0; c < 4; ++c) {
    bf8 w1f[2][4];
#pragma unroll
    for (int nt = 0; nt < 2; ++nt)
#pragma unroll
      for (int kf = 0; kf < 4; ++kf)
        w1f[nt][kf] = *reinterpret_cast<const bf8*>(
            &W1b[(size_t)(c * 128 + (2 * w + nt) * 16 + lc) * DD + kf * 32 + kg * 8]);
    f32x4 hac[5][2];
#pragma unroll
    for (int m = 0; m < 5; ++m)
#pragma unroll
      for (int n = 0; n < 2; ++n) hac[m][n] = (f32x4){0.f, 0.f, 0.f, 0.f};
#pragma unroll
    for (int mt = 0; mt < 5; ++mt) {
      const unsigned short* yp = Yb + (mt * 16 + lc) * 136 + kg * 8;
      bf8 a0 = *reinterpret_cast<const bf8*>(yp);
      bf8 a1 = *reinterpret_cast<const bf8*>(yp + 32);
      bf8 a2 = *reinterpret_cast<const bf8*>(yp + 64);
      bf8 a3 = *reinterpret_cast<const bf8*>(yp + 96);
#pragma unroll
      for (int nt = 0; nt < 2; ++nt) {
        hac[mt][nt] = __builtin_amdgcn_mfma_f32_16x16x32_bf16(a0, w1f[nt][0], hac[mt][nt], 0, 0, 0);
        hac[mt][nt] = __builtin_amdgcn_mfma_f32_16x16x32_bf16(a1, w1f[nt][1], hac[mt][nt], 0, 0, 0);
        hac[mt][nt] = __builtin_amdgcn_mfma_f32_16x16x32_bf16(a2, w1f[nt][2], hac[mt][nt], 0, 0, 0);
        hac[mt][nt] = __builtin_amdgcn_mfma_f32_16x16x32_bf16(a3, w1f[nt][3], hac[mt][nt], 0, 0, 0);
      }
    }
    float b1a = b1[c * 128 + c0], b1b = b1[c * 128 + c1];
    __syncthreads();
#pragma unroll
    for (int mt = 0; mt < 5; ++mt) {
      int rb = mt * 16 + kg * 4;
#pragma unroll
      for (int j = 0; j < 4; ++j) {
        int row = rb + j;
        Hb[row * 136 + c0] = f2bf(fmaxf(hac[mt][0][j] + b1a, 0.f));
        Hb[row * 136 + c1] = f2bf(fmaxf(hac[mt][1][j] + b1b, 0.f));
      }
    }
    __syncthreads();
    bf8 w2f[2][4];
#pragma unroll
    for (int nt = 0; nt < 2; ++nt)
#pragma unroll
      for (int kf = 0; kf < 4; ++kf)
        w2f[nt][kf] = *reinterpret_cast<const bf8*>(
            &W2b[(size_t)((2 * w + nt) * 16 + lc) * FF + c * 128 + kf * 32 + kg * 8]);
#pragma unroll
    for (int mt = 0; mt < 5; ++mt) {
      const unsigned short* hp = Hb + (mt * 16 + lc) * 136 + kg * 8;
      bf8 a0 = *reinterpret_cast<const bf8*>(hp);
      bf8 a1 = *reinterpret_cast<const bf8*>(hp + 32);
      bf8 a2 = *reinterpret_cast<const bf8*>(hp + 64);
      bf8 a3 = *reinterpret_cast<const bf8*>(hp + 96);
#pragma unroll
      for (int nt = 0; nt < 2; ++nt) {
        oac[mt][nt] = __builtin_amdgcn_mfma_f32_16x16x32_bf16(a0, w2f[nt][0], oac[mt][nt], 0, 0, 0);
        oac[mt][nt] = __builtin_amdgcn_mfma_f32_16x16x32_bf16(a1, w2f[nt][1], oac[mt][nt], 0, 0, 0);
        oac[mt][nt] = __builtin_amdgcn_mfma_f32_16x16x32_bf16(a2, w2f[nt][2], oac[mt][nt], 0, 0, 0);
        oac[mt][nt] = __builtin_amdgcn_mfma_f32_16x16x32_bf16(a3, w2f[nt][3], oac[mt][nt], 0, 0, 0);
      }
    }
  }
  __syncthreads();
  {
    float b2a = b2[c0], b2b = b2[c1];
#pragma unroll
    for (int mt = 0; mt < 5; ++mt) {
      int rb = mt * 16 + kg * 4;
#pragma unroll
      for (int j = 0; j < 4; ++j) {
        int row = rb + j;
        float v0 = zac[mt][0][j] + oac[mt][0][j] + b2a;
        float v1 = zac[mt][1][j] + oac[mt][1][j] + b2b;
        oac[mt][0][j] = v0; oac[mt][1][j] = v1;
        Yb[row * 136 + c0] = f2bf(v0);
        Yb[row * 136 + c1] = f2bf(v1);
      }
    }
  }
  __syncthreads();
  if (t < 160) {
    int row = t >> 1, hf = t & 1;
    const unsigned short* rp = Yb + row * 136 + hf * 64;
    float s = 0.f, s2 = 0.f;
#pragma unroll
    for (int c8 = 0; c8 < 8; ++c8) {
      bf8 v8 = *reinterpret_cast<const bf8*>(rp + c8 * 8);
#pragma unroll
      for (int j = 0; j < 8; ++j) {
        float f = bf2f((unsigned short)v8[j]);
        s += f; s2 += f * f;
      }
    }
    s += __shfl_xor(s, 1); s2 += __shfl_xor(s2, 1);
    if (!hf) {
      float mm = s * (1.f / 128.f);
      float vv = s2 * (1.f / 128.f) - mm * mm;
      mrow[row] = mm;
      rrow[row] = rsqrtf(vv + 1e-5f);
    }
  }
  __syncthreads();
  {
    float* fb = (float*)SH;
    float g2a = g2[c0], g2b = g2[c1], e2a = be2[c0], e2b = be2[c1];
#pragma unroll
    for (int mt = 0; mt < 5; ++mt) {
      int rb = mt * 16 + kg * 4;
#pragma unroll
      for (int j = 0; j < 4; ++j) {
        int row = rb + j;
        float mm = mrow[row], rr = rrow[row];
        fb[row * 132 + c0] = (oac[mt][0][j] - mm) * rr * g2a + e2a;
        fb[row * 132 + c1] = (oac[mt][1][j] - mm) * rr * g2b + e2b;
      }
    }
    __syncthreads();   // all overlay reads complete before out overwrites segment
    const size_t ob = (size_t)blockIdx.x * 16 * PD;
    for (int i = t; i < 10240; i += 256) {
      int pl = i / PD, rem = i - pl * PD;
      int d = rem / 5, a = rem - d * 5;
      out[ob + i] = fb[(pl * 5 + a) * 132 + d];
    }
  }
}

// ---------------------------------------------------------------------------
extern "C" void kernel_launch(void* const* d_in, const int* in_sizes, int n_in,
                              void* d_out, int out_size, void* d_ws, size_t ws_size,
                              hipStream_t stream) {
  (void)in_sizes; (void)n_in; (void)out_size; (void)ws_size;
  const float* tgt  = (const float*)d_in[0];
  const int*   idx  = (const int*)d_in[1];
  const float* dist = (const float*)d_in[3];
  const float* Wq   = (const float*)d_in[4];
  const float* Wk   = (const float*)d_in[5];
  const float* Wo   = (const float*)d_in[6];
  const float* W1   = (const float*)d_in[7];
  const float* b1f  = (const float*)d_in[8];
  const float* W2   = (const float*)d_in[9];
  const float* b2f  = (const float*)d_in[10];
  const float* g1   = (const float*)d_in[11];
  const float* be1  = (const float*)d_in[12];
  const float* g2   = (const float*)d_in[13];
  const float* be2  = (const float*)d_in[14];
  float* out = (float*)d_out;

  // ws (shorts): kqb [P][1280] | Wob | W1b | W2b | Wqb | Wkb  = 51.56 MB total
  unsigned short* kqb = (unsigned short*)d_ws;
  unsigned short* Wob = kqb + (size_t)PP * 1280;
  unsigned short* W1b = Wob + DD * DD;
  unsigned short* W2b = W1b + FF * DD;
  unsigned short* Wqb = W2b + FF * DD;
  unsigned short* Wkb = Wqb + DD * DD;
  unsigned short* ovl = (unsigned short*)d_out;   // segment overlay (x | t2)

  k_wconv  <<<256, 256, 0, stream>>>(Wo, W1, W2, Wq, Wk, Wob, W1b, W2b, Wqb, Wkb);
  k_xpose  <<<PP / 8, 320, 0, stream>>>(tgt, ovl);
  k_qk_gemm<<<ROWS / 80, 256, 0, stream>>>(ovl, Wqb, Wkb, kqb);
  k_attn   <<<PP, 256, 0, stream>>>(kqb, idx, dist, ovl);
  k_ffn_mfma<<<ROWS / 80, 256, 0, stream>>>(out, Wob, W1b, b1f, W2b, b2f,
                                            g1, be1, g2, be2);
}